// Round 1
// baseline (278.261 us; speedup 1.0000x reference)
//
#include <hip/hip_runtime.h>

// EdgeLoss: mean(|sobel_x(sr)-sobel_x(hr)| + |sobel_y(sr)-sobel_y(hr)|)
// = mean(|sobel_x(d)| + |sobel_y(d)|), d = sr - hr (conv linearity; the
// 180-deg kernel flip only flips sign, erased by abs).
// Separable: s = [1,2,1]*d (horiz), t = [1,0,-1]*d (horiz);
//            gx = [1,2,1]^T * t (vert), gy = [1,0,-1]^T * s (vert).
//
// R5: the R3/R4 register-batch plan never materialized (VGPR=64 vs ~110
// needed -> compiler re-serialized loads with waitcnts; wave lifetime
// ~49k cyc ~= 40 serial HBM latencies). Fix: async global->LDS DMA
// (global_load_lds, 16B/lane). The loads have NO register destination,
// so the scheduler cannot serialize them against a register window --
// all 20 wave-instructions issue back-to-back, one vmcnt(0) drain at the
// __syncthreads. LDS = 80 KB/block -> exactly 2 blocks/CU; the two
// resident blocks overlap DMA and compute phases. Full rows in LDS also
// kill the shuffle + exec-masked scalar-halo-load machinery: neighbors
// are plain LDS reads.

#define IMG_H 1024
#define IMG_W 1024
#define IMG_B 32
#define CH 8                    // output rows per block
#define NROW (CH + 2)           // rows staged (with vertical halo)
#define NCHUNK (IMG_H / CH)     // 128 -> grid (128, 32) = 4096 blocks

#define GLOBAL_PTR(p) ((const __attribute__((address_space(1))) void*)(p))
#define LDS_PTR(p)    ((__attribute__((address_space(3))) void*)(p))

__device__ __forceinline__ void row_st_lds(const float* __restrict__ a,
                                           const float* __restrict__ b,
                                           int x0, float m,
                                           float4& s, float4& t) {
    const float4 av = *reinterpret_cast<const float4*>(a + x0);   // ds_read_b128
    const float4 bv = *reinterpret_cast<const float4*>(b + x0);
    float4 d;
    d.x = (av.x - bv.x) * m;
    d.y = (av.y - bv.y) * m;
    d.z = (av.z - bv.z) * m;
    d.w = (av.w - bv.w) * m;
    // horizontal halo straight from LDS; zero at true image edges only
    const float dl = (x0 > 0)           ? (a[x0 - 1] - b[x0 - 1]) * m : 0.f;
    const float dr = (x0 + 4 < IMG_W)   ? (a[x0 + 4] - b[x0 + 4]) * m : 0.f;
    s.x = dl  + 2.f * d.x + d.y;
    s.y = d.x + 2.f * d.y + d.z;
    s.z = d.y + 2.f * d.z + d.w;
    s.w = d.z + 2.f * d.w + dr;
    t.x = dl  - d.y;
    t.y = d.x - d.z;
    t.z = d.y - d.w;
    t.w = d.z - dr;
}

__global__ __launch_bounds__(256) void edge_loss_kernel(
        const float* __restrict__ sr, const float* __restrict__ hr,
        float* __restrict__ out, float invN) {
    // 2 * 10 * 1024 * 4 B = 81920 B -> exactly 2 blocks/CU (160 KiB LDS).
    // No extra LDS: the cross-wave reduction reuses lA[0][0..3].
    __shared__ __align__(16) float lA[NROW][IMG_W];
    __shared__ __align__(16) float lB[NROW][IMG_W];

    const int chunk = blockIdx.x;
    const int b     = blockIdx.y;
    const int tid   = threadIdx.x;
    const int lane  = tid & 63;
    const int wave  = tid >> 6;
    const int x0    = tid * 4;          // this thread's 4-col strip
    const int wseg  = wave * 256;       // this wave's 256-col row segment
    const size_t img = (size_t)b * IMG_H * IMG_W;
    const int y0 = chunk * CH;

    // ---- DMA phase: 20 global_load_lds per wave, zero VGPR destinations,
    // zero intermediate waits. Each instruction moves 64 lanes x 16 B = 1 KB
    // (one wave's row segment), LDS dst = wave-uniform base + lane*16.
    #pragma unroll
    for (int r = 0; r < NROW; ++r) {
        const int yc = min(max(y0 - 1 + r, 0), IMG_H - 1);  // clamp, mask later
        const size_t off = img + (size_t)yc * IMG_W + wseg + lane * 4;
        __builtin_amdgcn_global_load_lds(GLOBAL_PTR(sr + off), LDS_PTR(&lA[r][wseg]), 16, 0, 0);
        __builtin_amdgcn_global_load_lds(GLOBAL_PTR(hr + off), LDS_PTR(&lB[r][wseg]), 16, 0, 0);
    }
    // Single drain point: compiler emits s_waitcnt vmcnt(0) before s_barrier.
    __syncthreads();

    // ---- compute phase: 3-row sliding s/t window read from LDS ----
    const float mtop = (y0 > 0) ? 1.f : 0.f;
    const float mbot = (y0 + CH < IMG_H) ? 1.f : 0.f;

    float4 s0, t0, s1, t1, s2, t2;
    row_st_lds(lA[0], lB[0], x0, mtop, s0, t0);
    row_st_lds(lA[1], lB[1], x0, 1.f,  s1, t1);

    float acc = 0.f;
    #pragma unroll
    for (int i = 2; i < NROW; ++i) {
        const float m = (i == NROW - 1) ? mbot : 1.f;
        row_st_lds(lA[i], lB[i], x0, m, s2, t2);

        float gx, gy;
        gx = t0.x + 2.f * t1.x + t2.x;  gy = s0.x - s2.x;  acc += fabsf(gx) + fabsf(gy);
        gx = t0.y + 2.f * t1.y + t2.y;  gy = s0.y - s2.y;  acc += fabsf(gx) + fabsf(gy);
        gx = t0.z + 2.f * t1.z + t2.z;  gy = s0.z - s2.z;  acc += fabsf(gx) + fabsf(gy);
        gx = t0.w + 2.f * t1.w + t2.w;  gy = s0.w - s2.w;  acc += fabsf(gx) + fabsf(gy);

        s0 = s1; t0 = t1; s1 = s2; t1 = t2;
    }

    // ---- reduction: wave shuffle -> LDS (reuse lA) -> 1 atomic/block ----
    #pragma unroll
    for (int off = 32; off > 0; off >>= 1)
        acc += __shfl_down(acc, off, 64);

    __syncthreads();                 // all LDS reads of lA/lB complete
    if (lane == 0) lA[0][wave] = acc;
    __syncthreads();
    if (tid == 0) {
        const float bsum = lA[0][0] + lA[0][1] + lA[0][2] + lA[0][3];
        atomicAdd(out, bsum * invN);
    }
}

extern "C" void kernel_launch(void* const* d_in, const int* in_sizes, int n_in,
                              void* d_out, int out_size, void* d_ws, size_t ws_size,
                              hipStream_t stream) {
    const float* sr = (const float*)d_in[0];
    const float* hr = (const float*)d_in[1];
    float* out = (float*)d_out;

    hipMemsetAsync(out, 0, sizeof(float), stream);

    dim3 grid(NCHUNK, IMG_B);
    const float invN = 1.0f / (float)((size_t)IMG_B * IMG_H * IMG_W);
    edge_loss_kernel<<<grid, 256, 0, stream>>>(sr, hr, out, invN);
}